// Round 1
// baseline (304.206 us; speedup 1.0000x reference)
//
#include <hip/hip_runtime.h>

#define N 8192
#define M 8192
#define D 256

typedef unsigned short ushort_t;
typedef __attribute__((ext_vector_type(8))) short short8;
typedef __attribute__((ext_vector_type(4))) float floatx4;

__device__ __forceinline__ unsigned short f2bf(float f) {
  unsigned int u = __float_as_uint(f);
  u += 0x7fffu + ((u >> 16) & 1u);   // round-to-nearest-even
  return (unsigned short)(u >> 16);
}

// One wave per row: fp32 norm (full precision) + bf16 cast of the row.
__global__ __launch_bounds__(256) void prep_kernel(const float* __restrict__ x,
                                                   const float* __restrict__ s,
                                                   ushort_t* __restrict__ xb,
                                                   ushort_t* __restrict__ sb,
                                                   float* __restrict__ xn,
                                                   float* __restrict__ sn) {
  int gw = blockIdx.x * 4 + (threadIdx.x >> 6);
  int lane = threadIdx.x & 63;
  const float* src;
  ushort_t* dst;
  float* nrm;
  int row;
  if (gw < N) { src = x; dst = xb; nrm = xn; row = gw; }
  else        { src = s; dst = sb; nrm = sn; row = gw - N; }
  float4 v = ((const float4*)(src + (size_t)row * D))[lane];  // 64 lanes x 4 = 256
  float ss = v.x * v.x + v.y * v.y + v.z * v.z + v.w * v.w;
  ushort4 o;
  o.x = f2bf(v.x); o.y = f2bf(v.y); o.z = f2bf(v.z); o.w = f2bf(v.w);
  *(ushort4*)(dst + (size_t)row * D + lane * 4) = o;
#pragma unroll
  for (int off = 32; off > 0; off >>= 1) ss += __shfl_down(ss, off);
  if (lane == 0) nrm[row] = ss;
}

// 128x128 C-tile, 4 waves (2x2), each wave 4x4 of 16x16x32 bf16 MFMA.
// global_load_lds width=16 staging; fused RBF epilogue.
__global__ __launch_bounds__(256) void rbf_gemm(const ushort_t* __restrict__ X,
                                                const ushort_t* __restrict__ S,
                                                const float* __restrict__ xn,
                                                const float* __restrict__ sn,
                                                float* __restrict__ out) {
  __shared__ __attribute__((aligned(16))) ushort_t As[128 * 32];
  __shared__ __attribute__((aligned(16))) ushort_t Bs[128 * 32];
  __shared__ float xnS[128];
  __shared__ float snS[128];

  const int tid = threadIdx.x;
  const int lane = tid & 63;
  const int wave = tid >> 6;
  const int bx = blockIdx.x;  // col block (support)
  const int by = blockIdx.y;  // row block (x)

  if (tid < 128) xnS[tid] = xn[by * 128 + tid];
  else           snS[tid - 128] = sn[bx * 128 + (tid - 128)];

  const int wr = (wave >> 1) * 64;  // wave row offset in tile
  const int wc = (wave & 1) * 64;   // wave col offset in tile

  // Staging: wave covers tile rows [wave*32, wave*32+32). Inst q in {0,1}:
  // lane l -> row wave*32 + q*16 + l/4, cols (l&3)*8 .. +8 (16 B).
  // LDS dest = wave-uniform base + lane*16 (lane-linear, row-major, no pad).
  const int srow = wave * 32 + (lane >> 2);
  const int scol = (lane & 3) * 8;
  const ushort_t* gA = X + (size_t)(by * 128 + srow) * D + scol;
  const ushort_t* gB = S + (size_t)(bx * 128 + srow) * D + scol;
  ushort_t* lA = As + wave * 1024;  // elems; +512 for inst q=1
  ushort_t* lB = Bs + wave * 1024;

  const int q4 = lane >> 4;   // 0..3
  const int m16 = lane & 15;  // 0..15

  floatx4 acc[4][4];
#pragma unroll
  for (int i = 0; i < 4; ++i)
#pragma unroll
    for (int j = 0; j < 4; ++j) acc[i][j] = (floatx4){0.f, 0.f, 0.f, 0.f};

#pragma unroll
  for (int kt = 0; kt < D / 32; ++kt) {
    const int k0 = kt * 32;
    __syncthreads();  // previous iter's readers done before overwrite
    __builtin_amdgcn_global_load_lds(
        (const __attribute__((address_space(1))) void*)(gA + k0),
        (__attribute__((address_space(3))) void*)(lA), 16, 0, 0);
    __builtin_amdgcn_global_load_lds(
        (const __attribute__((address_space(1))) void*)(gA + (size_t)16 * D + k0),
        (__attribute__((address_space(3))) void*)(lA + 512), 16, 0, 0);
    __builtin_amdgcn_global_load_lds(
        (const __attribute__((address_space(1))) void*)(gB + k0),
        (__attribute__((address_space(3))) void*)(lB), 16, 0, 0);
    __builtin_amdgcn_global_load_lds(
        (const __attribute__((address_space(1))) void*)(gB + (size_t)16 * D + k0),
        (__attribute__((address_space(3))) void*)(lB + 512), 16, 0, 0);
    __syncthreads();  // drains vmcnt before barrier (compiler-inserted)

    short8 a_frag[4], b_frag[4];
#pragma unroll
    for (int i = 0; i < 4; ++i)
      a_frag[i] = *(const short8*)(As + (wr + i * 16 + m16) * 32 + q4 * 8);
#pragma unroll
    for (int j = 0; j < 4; ++j)
      b_frag[j] = *(const short8*)(Bs + (wc + j * 16 + m16) * 32 + q4 * 8);
#pragma unroll
    for (int i = 0; i < 4; ++i)
#pragma unroll
      for (int j = 0; j < 4; ++j)
        acc[i][j] = __builtin_amdgcn_mfma_f32_16x16x32_bf16(a_frag[i], b_frag[j],
                                                            acc[i][j], 0, 0, 0);
  }

  // Epilogue: sq = ||x||^2 + ||s||^2 - 2*cross, clamped; out = exp(-sq/D).
  // C/D layout (m89/m91-verified): col = lane&15, row = (lane>>4)*4 + reg.
  const float cexp = -1.0f / (float)D;
#pragma unroll
  for (int i = 0; i < 4; ++i) {
#pragma unroll
    for (int j = 0; j < 4; ++j) {
#pragma unroll
      for (int r = 0; r < 4; ++r) {
        const int rl = wr + i * 16 + q4 * 4 + r;
        const int cl = wc + j * 16 + m16;
        float sq = xnS[rl] + snS[cl] - 2.0f * acc[i][j][r];
        sq = fmaxf(sq, 0.0f);
        out[(size_t)(by * 128 + rl) * M + (bx * 128 + cl)] = __expf(cexp * sq);
      }
    }
  }
}

extern "C" void kernel_launch(void* const* d_in, const int* in_sizes, int n_in,
                              void* d_out, int out_size, void* d_ws, size_t ws_size,
                              hipStream_t stream) {
  const float* x = (const float*)d_in[0];
  const float* s = (const float*)d_in[1];
  float* out = (float*)d_out;
  char* ws = (char*)d_ws;
  ushort_t* xb = (ushort_t*)ws;                           // 4 MB bf16 X
  ushort_t* sb = (ushort_t*)(ws + (size_t)N * D * 2);     // 4 MB bf16 S
  float* xn = (float*)(ws + (size_t)(N + M) * D * 2);     // 32 KB
  float* sn = xn + N;                                     // 32 KB

  prep_kernel<<<(N + M) / 4, 256, 0, stream>>>(x, s, xb, sb, xn, sn);
  dim3 grid(M / 128, N / 128);
  rbf_gemm<<<grid, 256, 0, stream>>>(xb, sb, xn, sn, out);
}

// Round 2
// 294.860 us; speedup vs baseline: 1.0317x; 1.0317x over previous
//
#include <hip/hip_runtime.h>

#define N 8192
#define M 8192
#define D 256

typedef unsigned short ushort_t;
typedef __attribute__((ext_vector_type(8))) short short8;
typedef __attribute__((ext_vector_type(4))) float floatx4;

__device__ __forceinline__ unsigned short f2bf(float f) {
  unsigned int u = __float_as_uint(f);
  u += 0x7fffu + ((u >> 16) & 1u);   // round-to-nearest-even
  return (unsigned short)(u >> 16);
}

// One wave per row: fp32 norm (full precision) + bf16 cast of the row.
__global__ __launch_bounds__(256) void prep_kernel(const float* __restrict__ x,
                                                   const float* __restrict__ s,
                                                   ushort_t* __restrict__ xb,
                                                   ushort_t* __restrict__ sb,
                                                   float* __restrict__ xn,
                                                   float* __restrict__ sn) {
  int gw = blockIdx.x * 4 + (threadIdx.x >> 6);
  int lane = threadIdx.x & 63;
  const float* src;
  ushort_t* dst;
  float* nrm;
  int row;
  if (gw < N) { src = x; dst = xb; nrm = xn; row = gw; }
  else        { src = s; dst = sb; nrm = sn; row = gw - N; }
  float4 v = ((const float4*)(src + (size_t)row * D))[lane];  // 64 lanes x 4 = 256
  float ss = v.x * v.x + v.y * v.y + v.z * v.z + v.w * v.w;
  ushort4 o;
  o.x = f2bf(v.x); o.y = f2bf(v.y); o.z = f2bf(v.z); o.w = f2bf(v.w);
  *(ushort4*)(dst + (size_t)row * D + lane * 4) = o;
#pragma unroll
  for (int off = 32; off > 0; off >>= 1) ss += __shfl_down(ss, off);
  if (lane == 0) nrm[row] = ss;
}

// 128x128 C-tile, 4 waves (2x2), each wave 4x4 of 16x16x32 bf16 MFMA.
// BK=128 per staging round (4 chunks of 32) -> only 2 rounds / 4 barriers for
// the whole K=256. LDS 64KB -> 2 blocks/CU so staging drains of one block
// overlap MFMA bursts of the other (m114 wave-level overlap).
__global__ __launch_bounds__(256, 2) void rbf_gemm(const ushort_t* __restrict__ X,
                                                   const ushort_t* __restrict__ S,
                                                   const float* __restrict__ xn,
                                                   const float* __restrict__ sn,
                                                   float* __restrict__ out) {
  // chunked layout: [chunk 0..3][row 0..127][k 0..31], lane-linear per
  // global_load_lds (wave-uniform base + lane*16B), no padding.
  __shared__ __attribute__((aligned(16))) ushort_t As[4 * 128 * 32];
  __shared__ __attribute__((aligned(16))) ushort_t Bs[4 * 128 * 32];
  __shared__ float xnS[128];
  __shared__ float snS[128];

  const int tid = threadIdx.x;
  const int lane = tid & 63;
  const int wave = tid >> 6;
  const int bx = blockIdx.x;  // col block (support)
  const int by = blockIdx.y;  // row block (x)

  if (tid < 128) xnS[tid] = xn[by * 128 + tid];
  else           snS[tid - 128] = sn[bx * 128 + (tid - 128)];

  const int wr = (wave >> 1) * 64;  // wave row offset in tile
  const int wc = (wave & 1) * 64;   // wave col offset in tile

  // Staging: wave covers tile rows [wave*32, wave*32+32). Inst q in {0,1}:
  // lane l -> row wave*32 + q*16 + l/4, cols (l&3)*8 .. +8 (16 B).
  const int srow = wave * 32 + (lane >> 2);
  const int scol = (lane & 3) * 8;
  const ushort_t* gA = X + (size_t)(by * 128 + srow) * D + scol;
  const ushort_t* gB = S + (size_t)(bx * 128 + srow) * D + scol;

  const int q4 = lane >> 4;   // 0..3
  const int m16 = lane & 15;  // 0..15

  floatx4 acc[4][4];
#pragma unroll
  for (int i = 0; i < 4; ++i)
#pragma unroll
    for (int j = 0; j < 4; ++j) acc[i][j] = (floatx4){0.f, 0.f, 0.f, 0.f};

#pragma unroll
  for (int r = 0; r < 2; ++r) {
    const int kb = r * 128;
    __syncthreads();  // previous round's readers done before overwrite
#pragma unroll
    for (int c = 0; c < 4; ++c) {
      const int k0 = kb + c * 32;
      ushort_t* lA = As + c * 4096 + wave * 1024;
      ushort_t* lB = Bs + c * 4096 + wave * 1024;
      __builtin_amdgcn_global_load_lds(
          (const __attribute__((address_space(1))) void*)(gA + k0),
          (__attribute__((address_space(3))) void*)(lA), 16, 0, 0);
      __builtin_amdgcn_global_load_lds(
          (const __attribute__((address_space(1))) void*)(gA + (size_t)16 * D + k0),
          (__attribute__((address_space(3))) void*)(lA + 512), 16, 0, 0);
      __builtin_amdgcn_global_load_lds(
          (const __attribute__((address_space(1))) void*)(gB + k0),
          (__attribute__((address_space(3))) void*)(lB), 16, 0, 0);
      __builtin_amdgcn_global_load_lds(
          (const __attribute__((address_space(1))) void*)(gB + (size_t)16 * D + k0),
          (__attribute__((address_space(3))) void*)(lB + 512), 16, 0, 0);
    }
    __syncthreads();  // compiler emits s_waitcnt vmcnt(0) before s_barrier

#pragma unroll
    for (int c = 0; c < 4; ++c) {
      const ushort_t* cA = As + c * 4096;
      const ushort_t* cB = Bs + c * 4096;
      short8 a_frag[4], b_frag[4];
#pragma unroll
      for (int i = 0; i < 4; ++i)
        a_frag[i] = *(const short8*)(cA + (wr + i * 16 + m16) * 32 + q4 * 8);
#pragma unroll
      for (int j = 0; j < 4; ++j)
        b_frag[j] = *(const short8*)(cB + (wc + j * 16 + m16) * 32 + q4 * 8);
#pragma unroll
      for (int i = 0; i < 4; ++i)
#pragma unroll
        for (int j = 0; j < 4; ++j)
          acc[i][j] = __builtin_amdgcn_mfma_f32_16x16x32_bf16(a_frag[i], b_frag[j],
                                                              acc[i][j], 0, 0, 0);
    }
  }

  // Epilogue: sq = ||x||^2 + ||s||^2 - 2*cross, clamped; out = exp(-sq/D).
  // C/D layout (m89/m91-verified): col = lane&15, row = (lane>>4)*4 + reg.
  const float cexp = -1.0f / (float)D;
#pragma unroll
  for (int i = 0; i < 4; ++i) {
#pragma unroll
    for (int j = 0; j < 4; ++j) {
#pragma unroll
      for (int r = 0; r < 4; ++r) {
        const int rl = wr + i * 16 + q4 * 4 + r;
        const int cl = wc + j * 16 + m16;
        float sq = xnS[rl] + snS[cl] - 2.0f * acc[i][j][r];
        sq = fmaxf(sq, 0.0f);
        out[(size_t)(by * 128 + rl) * M + (bx * 128 + cl)] = __expf(cexp * sq);
      }
    }
  }
}

extern "C" void kernel_launch(void* const* d_in, const int* in_sizes, int n_in,
                              void* d_out, int out_size, void* d_ws, size_t ws_size,
                              hipStream_t stream) {
  const float* x = (const float*)d_in[0];
  const float* s = (const float*)d_in[1];
  float* out = (float*)d_out;
  char* ws = (char*)d_ws;
  ushort_t* xb = (ushort_t*)ws;                           // 4 MB bf16 X
  ushort_t* sb = (ushort_t*)(ws + (size_t)N * D * 2);     // 4 MB bf16 S
  float* xn = (float*)(ws + (size_t)(N + M) * D * 2);     // 32 KB
  float* sn = xn + N;                                     // 32 KB

  prep_kernel<<<(N + M) / 4, 256, 0, stream>>>(x, s, xb, sb, xn, sn);
  dim3 grid(M / 128, N / 128);
  rbf_gemm<<<grid, 256, 0, stream>>>(xb, sb, xn, sn, out);
}